// Round 16
// baseline (269.725 us; speedup 1.0000x reference)
//
#include <hip/hip_runtime.h>
#include <math.h>

#define BLOCK 1024
#define MSTR 212   // mags row stride (f32): 4*odd -> float4-aligned, quad-rotating

typedef __attribute__((ext_vector_type(8))) short short8;
typedef __attribute__((ext_vector_type(16))) float f32x16;
typedef __attribute__((ext_vector_type(8))) float f32x8;

__device__ inline unsigned short f2bf(float x) {
    unsigned u = __float_as_uint(x);
    unsigned r = u + 0x7fffu + ((u >> 16) & 1u);
    return (unsigned short)(r >> 16);
}

struct ASplit { short8 h, l; };

// fast truncation split: 6 VALU per 2 values (perm-pack hi, sub, perm-pack lo)
__device__ inline ASplit splitA_fast(f32x8 v) {
    unsigned h[4], l[4];
    #pragma unroll
    for (int q = 0; q < 4; ++q) {
        unsigned u0 = __float_as_uint(v[2*q]);
        unsigned u1 = __float_as_uint(v[2*q+1]);
        h[q] = __builtin_amdgcn_perm(u1, u0, 0x07060302u);   // hi16(u0)|hi16(u1)<<16
        float r0 = v[2*q]   - __uint_as_float(u0 & 0xFFFF0000u);
        float r1 = v[2*q+1] - __uint_as_float(u1 & 0xFFFF0000u);
        l[q] = __builtin_amdgcn_perm(__float_as_uint(r1), __float_as_uint(r0), 0x07060302u);
    }
    ASplit r;
    r.h = __builtin_bit_cast(short8, *(uint4*)h);
    r.l = __builtin_bit_cast(short8, *(uint4*)l);
    return r;
}

__device__ inline f32x8 loadA8(const float* __restrict__ x, int i0) {
    f32x8 r;
    if (i0 >= 0 && i0 <= 15992) {
        float4 a0 = *(const float4*)(x + i0);
        float4 a1 = *(const float4*)(x + i0 + 4);
        r[0] = a0.x; r[1] = a0.y; r[2] = a0.z; r[3] = a0.w;
        r[4] = a1.x; r[5] = a1.y; r[6] = a1.z; r[7] = a1.w;
    } else {
        #pragma unroll
        for (int e = 0; e < 8; ++e) {
            int p = i0 + e;
            p = (p < 0) ? -p : p;
            p = (p > 15999) ? (31998 - p) : p;
            r[e] = x[p];
        }
    }
    return r;
}

__device__ inline void filter_params(int c, const float* low_hz_, const float* band_hz_,
                                     float* fctr, float* finv, int* fks, int* fke) {
    float lo = 50.0f + fabsf(low_hz_[c]);
    float hi = lo + 50.0f + fabsf(band_hz_[c]);
    hi = fminf(fmaxf(hi, 50.0f), 8000.0f);
    float ctr = 0.5f * (lo + hi);
    float hbw = 0.5f * (hi - lo);
    int ks = (int)ceilf(lo * 0.025f);
    if (ks < 0) ks = 0;
    while (40.0f * (float)ks < lo) ++ks;
    while (ks > 0 && 40.0f * (float)(ks - 1) >= lo) --ks;
    int ke = (int)floorf(hi * 0.025f);
    if (ke > 200) ke = 200;
    while (40.0f * (float)ke > hi) --ke;
    while (ke < 200 && 40.0f * (float)(ke + 1) <= hi) ++ke;
    fctr[c] = ctr;
    finv[c] = (hbw > 0.0f) ? (1.0f / hbw) : 0.0f;
    fks[c]  = ks;
    fke[c]  = ke;
}

// ---------------------------------------------------------------------------
// Kernel 1: filters output (64 x 201) -> tail of d_out.
// ---------------------------------------------------------------------------
__global__ void fse_filters(const float* __restrict__ low_hz_,
                            const float* __restrict__ band_hz_,
                            float* __restrict__ out)
{
    int idx = blockIdx.x * 256 + threadIdx.x;
    if (idx >= 64 * 201) return;
    int c = idx / 201;
    int k = idx - c * 201;
    float lo = 50.0f + fabsf(low_hz_[c]);
    float hi = lo + 50.0f + fabsf(band_hz_[c]);
    hi = fminf(fmaxf(hi, 50.0f), 8000.0f);
    float ctr = 0.5f * (lo + hi);
    float hbw = 0.5f * (hi - lo);
    float fq = 40.0f * (float)k;
    float resp = 1.0f - fabsf(fq - ctr) / hbw;
    out[idx] = (fq >= lo && fq <= hi) ? resp : 0.0f;
}

// ---------------------------------------------------------------------------
// Kernel 1b: B chunk-linear, BK=32: Bt[kc13][pl][part4][row448][8] bf16.
//   row j: j<=200 -> re bin j ; 224<=j<=424 -> im bin j-224 ; else 0.
// ---------------------------------------------------------------------------
__global__ void fse_setup_B(unsigned short* __restrict__ bt)
{
    int idx = blockIdx.x * 256 + threadIdx.x;   // 13*2*4*448*8 = 372736
    if (idx >= 372736) return;
    int e   = idx & 7;
    int t   = idx >> 3;
    int row = t % 448;
    int q   = t / 448;
    int p   = q & 3;
    int pl  = (q >> 2) & 1;
    int kc  = q >> 3;
    int n   = kc * 32 + p * 8 + e;
    float v = 0.0f;
    if (n < 400) {
        int bin = -1, isim = 0;
        if (row <= 200) bin = row;
        else if (row >= 224 && row <= 424) { bin = row - 224; isim = 1; }
        if (bin >= 0) {
            int a = (bin * n) % 400;
            float th = 6.283185307179586f * ((float)a / 400.0f);
            float sn, cs;
            sincosf(th, &sn, &cs);
            float wn = 0.5f - 0.5f * cosf(6.283185307179586f * ((float)n / 400.0f));
            v = isim ? (-wn * sn) : (wn * cs);
        }
    }
    unsigned short h = f2bf(v);
    float hf = __uint_as_float((unsigned)h << 16);
    unsigned short l = f2bf(v - hf);
    bt[idx] = pl ? l : h;
}

// ---------------------------------------------------------------------------
// Kernel 2: fully fused, ONE 1024-thread block per batch item.
//  R16: ZERO-LDS, BARRIER-FREE GEMM. 16 waves = 2 mg (64-row halves) x 8 pg;
//  pg<7 active: each owns 2 m-tiles x 1 (re,im) bin-tile pair (B dedup: each
//  B fragment feeds 6 MFMAs). B fragments read DIRECTLY from global (L2-
//  resident 745KB table; lane-consecutive 16B = coalesced 512B lines).
//  A from global, fast-split in-register. No LDS/barriers in the K-loop ->
//  waves fully async, 4-wave TLP + compiler pipelining cover L2 latency.
//  Register ledger: 64 AGPR acc + ~60 VGPR live -> fits the 128 cap that
//  16 co-resident waves require (R14 lesson).
//  Post phase (LDS mags/fbuf) identical to R15; mag-write mapping proven R14.
//  C layout (HW-verified m74): col = lane&31, row = (r&3)+8*(r>>2)+4*(lane>>5).
// ---------------------------------------------------------------------------
__global__ __launch_bounds__(1024, 4)
void fse_main(const float* __restrict__ wav,
              const float* __restrict__ low_hz_,
              const float* __restrict__ band_hz_,
              const float* __restrict__ ln_w,
              const float* __restrict__ ln_b,
              const unsigned short* __restrict__ Bt,
              float* __restrict__ out)
{
    // post-phase LDS only: mags[101][212] f32 | fbuf[64*101]
    __shared__ __align__(16) char smem[111504];
    float* mags = (float*)smem;
    float* fbuf = (float*)(smem + 85648);

    __shared__ float fctr[64], finv[64];
    __shared__ int   fks[64], fke[64];
    __shared__ float red[32];
    __shared__ float stats[2];

    const int b    = blockIdx.x;
    const int tid  = threadIdx.x;
    const int w    = tid >> 6;          // 0..15
    const int lane = tid & 63;
    const float* __restrict__ x = wav + b * 16000;

    if (tid < 64) filter_params(tid, low_hz_, band_hz_, fctr, finv, fks, fke);

    const int mg   = w >> 3;            // 0,1 : 64-row half of M=128
    const int pg   = w & 7;             // pair-group; pg<7 active
    const bool act = (pg < 7);
    const int jrow = lane & 31;
    const int g    = lane >> 5;
    const int roR  = pg * 32 + jrow;          // re tile pg (row in B chunk)
    const int roI  = (pg + 7) * 32 + jrow;    // im tile pg+7

    const int arow0 = 64 * mg + jrow;         // m-tile 0 of this half
    const int arow1 = 64 * mg + 32 + jrow;    // m-tile 1
    const int te0   = (arow0 <= 100) ? arow0 : 50;
    const int te1   = (arow1 <= 100) ? arow1 : 50;
    const int ab0   = 160 * te0 - 200 + g * 8;
    const int ab1   = 160 * te1 - 200 + g * 8;

    f32x16 accR[2], accI[2];            // [m-tile] x (re, im)
    #pragma unroll
    for (int i = 0; i < 2; ++i)
        #pragma unroll
        for (int e = 0; e < 16; ++e) { accR[i][e] = 0.0f; accI[i][e] = 0.0f; }

    if (act) {
        for (int kc = 0; kc < 13; ++kc) {
            const int kb = kc * 28672;           // chunk base (shorts)
            // A: load then split immediately (f32x8 dies at split)
            f32x8 a00 = loadA8(x, ab0 + kc * 32);
            f32x8 a01 = loadA8(x, ab0 + kc * 32 + 16);
            ASplit S00 = splitA_fast(a00);
            ASplit S01 = splitA_fast(a01);
            f32x8 a10 = loadA8(x, ab1 + kc * 32);
            f32x8 a11 = loadA8(x, ab1 + kc * 32 + 16);
            ASplit S10 = splitA_fast(a10);
            ASplit S11 = splitA_fast(a11);

            #pragma unroll
            for (int s = 0; s < 2; ++s) {
                const int part = s * 2 + g;
                const unsigned short* bh = Bt + kb + part * 3584;   // pl=0
                const unsigned short* bl = bh + 14336;              // pl=1
                short8 BhR = *(const short8*)(bh + roR * 8);
                short8 BlR = *(const short8*)(bl + roR * 8);
                short8 BhI = *(const short8*)(bh + roI * 8);
                short8 BlI = *(const short8*)(bl + roI * 8);
                const short8 Ah0 = s ? S01.h : S00.h;
                const short8 Al0 = s ? S01.l : S00.l;
                const short8 Ah1 = s ? S11.h : S10.h;
                const short8 Al1 = s ? S11.l : S10.l;
                accR[0] = __builtin_amdgcn_mfma_f32_32x32x16_bf16(Ah0, BhR, accR[0], 0, 0, 0);
                accR[0] = __builtin_amdgcn_mfma_f32_32x32x16_bf16(Ah0, BlR, accR[0], 0, 0, 0);
                accR[0] = __builtin_amdgcn_mfma_f32_32x32x16_bf16(Al0, BhR, accR[0], 0, 0, 0);
                accR[1] = __builtin_amdgcn_mfma_f32_32x32x16_bf16(Ah1, BhR, accR[1], 0, 0, 0);
                accR[1] = __builtin_amdgcn_mfma_f32_32x32x16_bf16(Ah1, BlR, accR[1], 0, 0, 0);
                accR[1] = __builtin_amdgcn_mfma_f32_32x32x16_bf16(Al1, BhR, accR[1], 0, 0, 0);
                accI[0] = __builtin_amdgcn_mfma_f32_32x32x16_bf16(Ah0, BhI, accI[0], 0, 0, 0);
                accI[0] = __builtin_amdgcn_mfma_f32_32x32x16_bf16(Ah0, BlI, accI[0], 0, 0, 0);
                accI[0] = __builtin_amdgcn_mfma_f32_32x32x16_bf16(Al0, BhI, accI[0], 0, 0, 0);
                accI[1] = __builtin_amdgcn_mfma_f32_32x32x16_bf16(Ah1, BhI, accI[1], 0, 0, 0);
                accI[1] = __builtin_amdgcn_mfma_f32_32x32x16_bf16(Ah1, BlI, accI[1], 0, 0, 0);
                accI[1] = __builtin_amdgcn_mfma_f32_32x32x16_bf16(Al1, BhI, accI[1], 0, 0, 0);
            }
        }
    }

    __syncthreads();   // first block-wide sync: GEMM done, fctr ready, smem free

    // ---- magnitude fully in-register, single LDS write pass (mapping: R14)
    if (act) {
        const int k = pg * 32 + jrow;
        if (k <= 200) {
            #pragma unroll
            for (int mtl = 0; mtl < 2; ++mtl) {
                #pragma unroll
                for (int r = 0; r < 16; ++r) {
                    int t = 64 * mg + 32 * mtl + (r & 3) + 8 * (r >> 2) + 4 * g;
                    if (t <= 100) {
                        float re = accR[mtl][r];
                        float im = accI[mtl][r];
                        mags[t * MSTR + k] = sqrtf(re * re + im * im);
                    }
                }
            }
        }
    }
    // zero guard columns 201..211 (float4 over-read target)
    for (int i = tid; i < 101 * 11; i += BLOCK) {
        int row = i / 11;
        int col = 201 + (i - row * 11);
        mags[row * MSTR + col] = 0.0f;
    }
    __syncthreads();

    // ---- filterbank: lane = t, 4 channels per wave, float4 reads,
    //      mask-free triangle: resp>0 iff low<f<high (boundary = 0 exactly).
    {
        const int t0 = lane;
        const int t1v = 64 + lane;
        const int t1 = (t1v <= 100) ? t1v : 100;
        #pragma unroll
        for (int i = 0; i < 4; ++i) {
            const int c = w * 4 + i;
            const float ctr = fctr[c];
            const float inv = finv[c];
            const int ks4 = fks[c] & ~3;
            const int ke  = fke[c];
            float a0 = 0.0f, a1 = 0.0f;
            for (int k4 = ks4; k4 <= ke; k4 += 4) {
                float4 m0 = *(const float4*)&mags[t0 * MSTR + k4];
                float4 m1 = *(const float4*)&mags[t1 * MSTR + k4];
                #pragma unroll
                for (int j = 0; j < 4; ++j) {
                    float resp = fmaxf(1.0f - fabsf(40.0f * (float)(k4 + j) - ctr) * inv, 0.0f);
                    float mj0 = (j == 0) ? m0.x : (j == 1) ? m0.y : (j == 2) ? m0.z : m0.w;
                    float mj1 = (j == 0) ? m1.x : (j == 1) ? m1.y : (j == 2) ? m1.z : m1.w;
                    a0 = fmaf(resp, mj0, a0);
                    a1 = fmaf(resp, mj1, a1);
                }
            }
            fbuf[c * 101 + t0] = a0;
            if (t1v <= 100) fbuf[c * 101 + t1v] = a1;
        }
    }
    __syncthreads();

    // ---- global LayerNorm (one-pass: sum + sumsq)
    float s = 0.0f, ss = 0.0f;
    for (int i = tid; i < 6464; i += BLOCK) {
        float vv = fbuf[i];
        s += vv;
        ss = fmaf(vv, vv, ss);
    }
    #pragma unroll
    for (int off = 32; off > 0; off >>= 1) {
        s  += __shfl_down(s,  off, 64);
        ss += __shfl_down(ss, off, 64);
    }
    if (lane == 0) { red[w] = s; red[16 + w] = ss; }
    __syncthreads();
    if (tid == 0) {
        float ts = 0.0f, tss = 0.0f;
        for (int i = 0; i < 16; ++i) { ts += red[i]; tss += red[16 + i]; }
        float mu = ts * (1.0f / 6464.0f);
        stats[0] = mu;
        stats[1] = tss * (1.0f / 6464.0f) - mu * mu;
    }
    __syncthreads();
    const float mu   = stats[0];
    const float isig = 1.0f / sqrtf(stats[1] + 1e-5f);

    // ---- log-energy + interp 101->64 + transposed store
    for (int idx = tid; idx < 4096; idx += BLOCK) {
        const int to = idx >> 6;
        const int c  = idx & 63;
        float pos = ((float)to + 0.5f) * 1.578125f - 0.5f;
        pos = fminf(fmaxf(pos, 0.0f), 100.0f);
        int i0 = (int)floorf(pos);
        int i1 = i0 + 1; if (i1 > 100) i1 = 100;
        float fr = pos - (float)i0;
        float wc = ln_w[c], bc = ln_b[c];
        float x0 = fbuf[c * 101 + i0];
        float x1 = fbuf[c * 101 + i1];
        float y0 = fmaf(wc, (x0 - mu) * isig, bc);
        float y1 = fmaf(wc, (x1 - mu) * isig, bc);
        float l0 = log10f(fmaf(y0, y0, 1e-6f));
        float l1 = log10f(fmaf(y1, y1, 1e-6f));
        out[b * 4096 + idx] = l0 * (1.0f - fr) + l1 * fr;
    }
}

extern "C" void kernel_launch(void* const* d_in, const int* in_sizes, int n_in,
                              void* d_out, int out_size, void* d_ws, size_t ws_size,
                              hipStream_t stream)
{
    const float* wav = (const float*)d_in[0];
    const float* lo  = (const float*)d_in[1];
    const float* bd  = (const float*)d_in[2];
    const float* lw  = (const float*)d_in[3];
    const float* lb  = (const float*)d_in[4];
    float* out = (float*)d_out;

    fse_filters<<<(64 * 201 + 255) / 256, 256, 0, stream>>>(lo, bd, out + 1024 * 4096);

    unsigned short* Bts = (unsigned short*)d_ws;   // 745472 B needed; ws proven larger
    fse_setup_B<<<(372736 + 255) / 256, 256, 0, stream>>>(Bts);
    fse_main<<<1024, BLOCK, 0, stream>>>(wav, lo, bd, lw, lb, Bts, out);
}

// Round 17
// 205.212 us; speedup vs baseline: 1.3144x; 1.3144x over previous
//
#include <hip/hip_runtime.h>
#include <math.h>

#define BLOCK 1024
#define MSTR 212   // mags row stride (f32): 4*odd -> float4-aligned, quad-rotating

typedef __attribute__((ext_vector_type(8))) short short8;
typedef __attribute__((ext_vector_type(16))) float f32x16;
typedef __attribute__((ext_vector_type(8))) float f32x8;

__device__ inline unsigned short f2bf(float x) {
    unsigned u = __float_as_uint(x);
    unsigned r = u + 0x7fffu + ((u >> 16) & 1u);
    return (unsigned short)(r >> 16);
}

struct ASplit { short8 h, l; };

// fast truncation split: 6 VALU per 2 values (perm-pack hi, sub, perm-pack lo)
__device__ inline ASplit splitA_fast(f32x8 v) {
    unsigned h[4], l[4];
    #pragma unroll
    for (int q = 0; q < 4; ++q) {
        unsigned u0 = __float_as_uint(v[2*q]);
        unsigned u1 = __float_as_uint(v[2*q+1]);
        h[q] = __builtin_amdgcn_perm(u1, u0, 0x07060302u);   // hi16(u0)|hi16(u1)<<16
        float r0 = v[2*q]   - __uint_as_float(u0 & 0xFFFF0000u);
        float r1 = v[2*q+1] - __uint_as_float(u1 & 0xFFFF0000u);
        l[q] = __builtin_amdgcn_perm(__float_as_uint(r1), __float_as_uint(r0), 0x07060302u);
    }
    ASplit r;
    r.h = __builtin_bit_cast(short8, *(uint4*)h);
    r.l = __builtin_bit_cast(short8, *(uint4*)l);
    return r;
}

__device__ inline f32x8 loadA8(const float* __restrict__ x, int i0) {
    f32x8 r;
    if (i0 >= 0 && i0 <= 15992) {
        float4 a0 = *(const float4*)(x + i0);
        float4 a1 = *(const float4*)(x + i0 + 4);
        r[0] = a0.x; r[1] = a0.y; r[2] = a0.z; r[3] = a0.w;
        r[4] = a1.x; r[5] = a1.y; r[6] = a1.z; r[7] = a1.w;
    } else {
        #pragma unroll
        for (int e = 0; e < 8; ++e) {
            int p = i0 + e;
            p = (p < 0) ? -p : p;
            p = (p > 15999) ? (31998 - p) : p;
            r[e] = x[p];
        }
    }
    return r;
}

__device__ inline void filter_params(int c, const float* low_hz_, const float* band_hz_,
                                     float* fctr, float* finv, int* fks, int* fke) {
    float lo = 50.0f + fabsf(low_hz_[c]);
    float hi = lo + 50.0f + fabsf(band_hz_[c]);
    hi = fminf(fmaxf(hi, 50.0f), 8000.0f);
    float ctr = 0.5f * (lo + hi);
    float hbw = 0.5f * (hi - lo);
    int ks = (int)ceilf(lo * 0.025f);
    if (ks < 0) ks = 0;
    while (40.0f * (float)ks < lo) ++ks;
    while (ks > 0 && 40.0f * (float)(ks - 1) >= lo) --ks;
    int ke = (int)floorf(hi * 0.025f);
    if (ke > 200) ke = 200;
    while (40.0f * (float)ke > hi) --ke;
    while (ke < 200 && 40.0f * (float)(ke + 1) <= hi) ++ke;
    fctr[c] = ctr;
    finv[c] = (hbw > 0.0f) ? (1.0f / hbw) : 0.0f;
    fks[c]  = ks;
    fke[c]  = ke;
}

// ---------------------------------------------------------------------------
// Kernel 1: filters output (64 x 201) -> tail of d_out.
// ---------------------------------------------------------------------------
__global__ void fse_filters(const float* __restrict__ low_hz_,
                            const float* __restrict__ band_hz_,
                            float* __restrict__ out)
{
    int idx = blockIdx.x * 256 + threadIdx.x;
    if (idx >= 64 * 201) return;
    int c = idx / 201;
    int k = idx - c * 201;
    float lo = 50.0f + fabsf(low_hz_[c]);
    float hi = lo + 50.0f + fabsf(band_hz_[c]);
    hi = fminf(fmaxf(hi, 50.0f), 8000.0f);
    float ctr = 0.5f * (lo + hi);
    float hbw = 0.5f * (hi - lo);
    float fq = 40.0f * (float)k;
    float resp = 1.0f - fabsf(fq - ctr) / hbw;
    out[idx] = (fq >= lo && fq <= hi) ? resp : 0.0f;
}

// ---------------------------------------------------------------------------
// Kernel 1b: B chunk-linear, BK=32: Bt[kc13][pl][part4][row448][8] bf16.
//   row j: j<=200 -> re bin j ; 224<=j<=424 -> im bin j-224 ; else 0.
// ---------------------------------------------------------------------------
__global__ void fse_setup_B(unsigned short* __restrict__ bt)
{
    int idx = blockIdx.x * 256 + threadIdx.x;   // 13*2*4*448*8 = 372736
    if (idx >= 372736) return;
    int e   = idx & 7;
    int t   = idx >> 3;
    int row = t % 448;
    int q   = t / 448;
    int p   = q & 3;
    int pl  = (q >> 2) & 1;
    int kc  = q >> 3;
    int n   = kc * 32 + p * 8 + e;
    float v = 0.0f;
    if (n < 400) {
        int bin = -1, isim = 0;
        if (row <= 200) bin = row;
        else if (row >= 224 && row <= 424) { bin = row - 224; isim = 1; }
        if (bin >= 0) {
            int a = (bin * n) % 400;
            float th = 6.283185307179586f * ((float)a / 400.0f);
            float sn, cs;
            sincosf(th, &sn, &cs);
            float wn = 0.5f - 0.5f * cosf(6.283185307179586f * ((float)n / 400.0f));
            v = isim ? (-wn * sn) : (wn * cs);
        }
    }
    unsigned short h = f2bf(v);
    float hf = __uint_as_float((unsigned)h << 16);
    unsigned short l = f2bf(v - hf);
    bt[idx] = pl ? l : h;
}

// ---------------------------------------------------------------------------
// K-step macro — R13/R15 proven structure + T5 setprio around MFMA cluster.
// ---------------------------------------------------------------------------
#define KSTEP(KC, CUROFF, A0c, A1c, A0n, A1n, PRE)                            \
  {                                                                           \
    asm volatile("s_waitcnt vmcnt(0)" ::: "memory");                          \
    __builtin_amdgcn_s_barrier();                                             \
    __builtin_amdgcn_sched_barrier(0);                                        \
    if (PRE) {                                                                \
      A0n = loadA8(x, ab + ((KC) + 1) * 32);                                  \
      A1n = loadA8(x, ab + ((KC) + 1) * 32 + 16);                             \
      const uint4* _src = btg + ((KC) + 1) * 3584;                            \
      const int _bufo = (CUROFF) ^ 57344;                                     \
      _Pragma("unroll")                                                       \
      for (int _i = 0; _i < 4; ++_i) {                                        \
        int _idx = _i * 1024 + tid;                                           \
        if (_idx < 3584) {                                                    \
          __builtin_amdgcn_global_load_lds(                                   \
              (const __attribute__((address_space(1))) unsigned*)(_src + _idx), \
              (__attribute__((address_space(3))) unsigned*)(smem + _bufo + _idx * 16), \
              16, 0, 0);                                                      \
        }                                                                     \
      }                                                                       \
    }                                                                         \
    ASplit _S0 = splitA_fast(A0c);                                            \
    ASplit _S1 = splitA_fast(A1c);                                            \
    const unsigned short* _bs = (const unsigned short*)(smem + (CUROFF));     \
    __builtin_amdgcn_s_setprio(1);                                            \
    _Pragma("unroll")                                                         \
    for (int _s = 0; _s < 2; ++_s) {                                          \
      const short8 _Ah = _s ? _S1.h : _S0.h;                                  \
      const short8 _Al = _s ? _S1.l : _S0.l;                                  \
      const int _part = _s * 2 + g;                                           \
      const int _bhof = _part * 3584;                                         \
      const int _blof = (4 + _part) * 3584;                                   \
      _Pragma("unroll")                                                       \
      for (int _i2 = 0; _i2 < 2; ++_i2) {                                     \
        if (_i2 < cnt) {                                                      \
          const int _p = pbase + _i2;                                         \
          const int _roR = _p * 32 + jrow;                                    \
          const int _roI = (_p + 7) * 32 + jrow;                              \
          short8 _BhR = *(const short8*)(_bs + _bhof + _roR * 8);             \
          short8 _BlR = *(const short8*)(_bs + _blof + _roR * 8);             \
          short8 _BhI = *(const short8*)(_bs + _bhof + _roI * 8);             \
          short8 _BlI = *(const short8*)(_bs + _blof + _roI * 8);             \
          accR[_i2] = __builtin_amdgcn_mfma_f32_32x32x16_bf16(_Ah, _BhR, accR[_i2], 0, 0, 0); \
          accR[_i2] = __builtin_amdgcn_mfma_f32_32x32x16_bf16(_Ah, _BlR, accR[_i2], 0, 0, 0); \
          accR[_i2] = __builtin_amdgcn_mfma_f32_32x32x16_bf16(_Al, _BhR, accR[_i2], 0, 0, 0); \
          accI[_i2] = __builtin_amdgcn_mfma_f32_32x32x16_bf16(_Ah, _BhI, accI[_i2], 0, 0, 0); \
          accI[_i2] = __builtin_amdgcn_mfma_f32_32x32x16_bf16(_Ah, _BlI, accI[_i2], 0, 0, 0); \
          accI[_i2] = __builtin_amdgcn_mfma_f32_32x32x16_bf16(_Al, _BhI, accI[_i2], 0, 0, 0); \
        }                                                                     \
      }                                                                       \
    }                                                                         \
    __builtin_amdgcn_s_setprio(0);                                            \
    asm volatile("s_waitcnt lgkmcnt(0)" ::: "memory");                        \
    __builtin_amdgcn_sched_barrier(0);                                        \
  }

// ---------------------------------------------------------------------------
// Kernel 2: fully fused, ONE 1024-thread block per batch item.
//  GEMM: R13/R15 structure (16 waves = 4 mt x 4 pq; counted-wait raw
//  barriers; A one-kc-ahead in two named register sets) + T5 setprio.
//  Post: float4 filterbank (MSTR 212, guard cols zeroed), one-pass LN.
// ---------------------------------------------------------------------------
__global__ __launch_bounds__(1024, 4)
void fse_main(const float* __restrict__ wav,
              const float* __restrict__ low_hz_,
              const float* __restrict__ band_hz_,
              const float* __restrict__ ln_w,
              const float* __restrict__ ln_b,
              const unsigned short* __restrict__ Bt,
              float* __restrict__ out)
{
    // GEMM: [0,57344) buf0 | [57344,114688) buf1
    // post: [0,85648) mags[101][212] f32 | [85648,111504) fbuf[64*101]
    __shared__ __align__(16) char smem[114688];
    float* mags = (float*)smem;
    float* fbuf = (float*)(smem + 85648);

    __shared__ float fctr[64], finv[64];
    __shared__ int   fks[64], fke[64];
    __shared__ float red[32];
    __shared__ float stats[2];

    const int b    = blockIdx.x;
    const int tid  = threadIdx.x;
    const int w    = tid >> 6;          // 0..15
    const int lane = tid & 63;
    const float* __restrict__ x = wav + b * 16000;

    if (tid < 64) filter_params(tid, low_hz_, band_hz_, fctr, finv, fks, fke);

    const int mt    = w >> 2;           // 0..3 : rows 32*mt .. 32*mt+31
    const int pq    = w & 3;            // pair-group
    const int pbase = pq * 2;           // pairs {0,1},{2,3},{4,5},{6}
    const int cnt   = (pq < 3) ? 2 : 1;
    const int jrow  = lane & 31;
    const int g     = lane >> 5;

    const int arow = 32 * mt + jrow;
    const int te   = (arow <= 100) ? arow : 50;
    const int ab   = 160 * te - 200 + g * 8;     // + kc*32 + s*16

    const uint4* __restrict__ btg = (const uint4*)Bt;   // 3584 uint4 per chunk

    // ---- prologue: A(0) into aE; DMA chunk 0 into buf0 (waited in KSTEP 0)
    f32x8 aE0 = loadA8(x, ab);
    f32x8 aE1 = loadA8(x, ab + 16);
    f32x8 aO0, aO1;
    {
        #pragma unroll
        for (int i = 0; i < 4; ++i) {
            int idx = i * 1024 + tid;
            if (idx < 3584) {
                __builtin_amdgcn_global_load_lds(
                    (const __attribute__((address_space(1))) unsigned*)(btg + idx),
                    (__attribute__((address_space(3))) unsigned*)(smem + idx * 16),
                    16, 0, 0);
            }
        }
    }

    f32x16 accR[2], accI[2];
    #pragma unroll
    for (int i = 0; i < 2; ++i)
        #pragma unroll
        for (int e = 0; e < 16; ++e) { accR[i][e] = 0.0f; accI[i][e] = 0.0f; }

    KSTEP(0,  0,     aE0, aE1, aO0, aO1, true)
    KSTEP(1,  57344, aO0, aO1, aE0, aE1, true)
    KSTEP(2,  0,     aE0, aE1, aO0, aO1, true)
    KSTEP(3,  57344, aO0, aO1, aE0, aE1, true)
    KSTEP(4,  0,     aE0, aE1, aO0, aO1, true)
    KSTEP(5,  57344, aO0, aO1, aE0, aE1, true)
    KSTEP(6,  0,     aE0, aE1, aO0, aO1, true)
    KSTEP(7,  57344, aO0, aO1, aE0, aE1, true)
    KSTEP(8,  0,     aE0, aE1, aO0, aO1, true)
    KSTEP(9,  57344, aO0, aO1, aE0, aE1, true)
    KSTEP(10, 0,     aE0, aE1, aO0, aO1, true)
    KSTEP(11, 57344, aO0, aO1, aE0, aE1, true)
    KSTEP(12, 0,     aE0, aE1, aO0, aO1, false)

    __syncthreads();   // GEMM done; smem reusable as mags/fbuf

    // ---- magnitude fully in-register, single LDS write pass
    #pragma unroll
    for (int i = 0; i < 2; ++i) {
        if (i < cnt) {
            const int k = (pbase + i) * 32 + jrow;
            if (k <= 200) {
                #pragma unroll
                for (int r = 0; r < 16; ++r) {
                    int t = 32 * mt + (r & 3) + 8 * (r >> 2) + 4 * g;
                    if (t <= 100) {
                        float re = accR[i][r];
                        float im = accI[i][r];
                        mags[t * MSTR + k] = sqrtf(re * re + im * im);
                    }
                }
            }
        }
    }
    // zero guard columns 201..211 (float4 over-read target)
    for (int i = tid; i < 101 * 11; i += BLOCK) {
        int row = i / 11;
        int col = 201 + (i - row * 11);
        mags[row * MSTR + col] = 0.0f;
    }
    __syncthreads();

    // ---- filterbank: lane = t, 4 channels per wave, float4 reads,
    //      mask-free triangle: resp>0 iff low<f<high (boundary = 0 exactly).
    {
        const int t0 = lane;
        const int t1v = 64 + lane;
        const int t1 = (t1v <= 100) ? t1v : 100;
        #pragma unroll
        for (int i = 0; i < 4; ++i) {
            const int c = w * 4 + i;
            const float ctr = fctr[c];
            const float inv = finv[c];
            const int ks4 = fks[c] & ~3;
            const int ke  = fke[c];
            float a0 = 0.0f, a1 = 0.0f;
            for (int k4 = ks4; k4 <= ke; k4 += 4) {
                float4 m0 = *(const float4*)&mags[t0 * MSTR + k4];
                float4 m1 = *(const float4*)&mags[t1 * MSTR + k4];
                #pragma unroll
                for (int j = 0; j < 4; ++j) {
                    float resp = fmaxf(1.0f - fabsf(40.0f * (float)(k4 + j) - ctr) * inv, 0.0f);
                    float mj0 = (j == 0) ? m0.x : (j == 1) ? m0.y : (j == 2) ? m0.z : m0.w;
                    float mj1 = (j == 0) ? m1.x : (j == 1) ? m1.y : (j == 2) ? m1.z : m1.w;
                    a0 = fmaf(resp, mj0, a0);
                    a1 = fmaf(resp, mj1, a1);
                }
            }
            fbuf[c * 101 + t0] = a0;
            if (t1v <= 100) fbuf[c * 101 + t1v] = a1;
        }
    }
    __syncthreads();

    // ---- global LayerNorm (one-pass: sum + sumsq)
    float s = 0.0f, ss = 0.0f;
    for (int i = tid; i < 6464; i += BLOCK) {
        float vv = fbuf[i];
        s += vv;
        ss = fmaf(vv, vv, ss);
    }
    #pragma unroll
    for (int off = 32; off > 0; off >>= 1) {
        s  += __shfl_down(s,  off, 64);
        ss += __shfl_down(ss, off, 64);
    }
    if (lane == 0) { red[w] = s; red[16 + w] = ss; }
    __syncthreads();
    if (tid == 0) {
        float ts = 0.0f, tss = 0.0f;
        for (int i = 0; i < 16; ++i) { ts += red[i]; tss += red[16 + i]; }
        float mu = ts * (1.0f / 6464.0f);
        stats[0] = mu;
        stats[1] = tss * (1.0f / 6464.0f) - mu * mu;
    }
    __syncthreads();
    const float mu   = stats[0];
    const float isig = 1.0f / sqrtf(stats[1] + 1e-5f);

    // ---- log-energy + interp 101->64 + transposed store
    for (int idx = tid; idx < 4096; idx += BLOCK) {
        const int to = idx >> 6;
        const int c  = idx & 63;
        float pos = ((float)to + 0.5f) * 1.578125f - 0.5f;
        pos = fminf(fmaxf(pos, 0.0f), 100.0f);
        int i0 = (int)floorf(pos);
        int i1 = i0 + 1; if (i1 > 100) i1 = 100;
        float fr = pos - (float)i0;
        float wc = ln_w[c], bc = ln_b[c];
        float x0 = fbuf[c * 101 + i0];
        float x1 = fbuf[c * 101 + i1];
        float y0 = fmaf(wc, (x0 - mu) * isig, bc);
        float y1 = fmaf(wc, (x1 - mu) * isig, bc);
        float l0 = log10f(fmaf(y0, y0, 1e-6f));
        float l1 = log10f(fmaf(y1, y1, 1e-6f));
        out[b * 4096 + idx] = l0 * (1.0f - fr) + l1 * fr;
    }
}

extern "C" void kernel_launch(void* const* d_in, const int* in_sizes, int n_in,
                              void* d_out, int out_size, void* d_ws, size_t ws_size,
                              hipStream_t stream)
{
    const float* wav = (const float*)d_in[0];
    const float* lo  = (const float*)d_in[1];
    const float* bd  = (const float*)d_in[2];
    const float* lw  = (const float*)d_in[3];
    const float* lb  = (const float*)d_in[4];
    float* out = (float*)d_out;

    fse_filters<<<(64 * 201 + 255) / 256, 256, 0, stream>>>(lo, bd, out + 1024 * 4096);

    unsigned short* Bts = (unsigned short*)d_ws;   // 745472 B needed; ws proven larger
    fse_setup_B<<<(372736 + 255) / 256, 256, 0, stream>>>(Bts);
    fse_main<<<1024, BLOCK, 0, stream>>>(wav, lo, bd, lw, lb, Bts, out);
}